// Round 1
// baseline (749.391 us; speedup 1.0000x reference)
//
#include <hip/hip_runtime.h>

// TemporalGCN: 2x GCNConv(64->64) + relu, global_mean_pool(64 graphs), linear 64->64.
// Strategy: build CSR-by-dst once (counting sort), pre-scale y = (x@W)*dinv,
// aggregate per node with one wave (lane = feature), no float atomics in the
// message-passing path.

#define DF 64

// ---------------- CSR build ----------------

__global__ void hist_kernel(const int* __restrict__ dst, int* __restrict__ counts, int E) {
    int stride = gridDim.x * blockDim.x;
    for (int e = blockIdx.x * blockDim.x + threadIdx.x; e < E; e += stride)
        atomicAdd(&counts[dst[e]], 1);
}

__global__ void scan_a(const int* __restrict__ counts, int* __restrict__ blockSums, int n) {
    __shared__ int lds[256];
    int base = blockIdx.x * 1024 + threadIdx.x * 4;
    int s = 0;
#pragma unroll
    for (int j = 0; j < 4; j++) {
        int i = base + j;
        if (i < n) s += counts[i];
    }
    lds[threadIdx.x] = s;
    __syncthreads();
    for (int off = 128; off > 0; off >>= 1) {
        if (threadIdx.x < off) lds[threadIdx.x] += lds[threadIdx.x + off];
        __syncthreads();
    }
    if (threadIdx.x == 0) blockSums[blockIdx.x] = lds[0];
}

// single block; B <= 256
__global__ void scan_b(const int* __restrict__ blockSums, int* __restrict__ blockOffsets,
                       int* __restrict__ offsets_end, int B) {
    __shared__ int lds[256];
    int v = (threadIdx.x < B) ? blockSums[threadIdx.x] : 0;
    lds[threadIdx.x] = v;
    __syncthreads();
    for (int off = 1; off < 256; off <<= 1) {
        int t = (threadIdx.x >= off) ? lds[threadIdx.x - off] : 0;
        __syncthreads();
        lds[threadIdx.x] += t;
        __syncthreads();
    }
    if (threadIdx.x < B) blockOffsets[threadIdx.x] = lds[threadIdx.x] - v;
    if (threadIdx.x == 255) offsets_end[0] = lds[255];  // total (= E)
}

__global__ void scan_c(const int* __restrict__ counts, const int* __restrict__ blockOffsets,
                       int* __restrict__ offsets, int* __restrict__ cursor, int n) {
    __shared__ int lds[256];
    int base = blockIdx.x * 1024 + threadIdx.x * 4;
    int v[4];
    int s = 0;
#pragma unroll
    for (int j = 0; j < 4; j++) {
        int i = base + j;
        v[j] = (i < n) ? counts[i] : 0;
        s += v[j];
    }
    lds[threadIdx.x] = s;
    __syncthreads();
    for (int off = 1; off < 256; off <<= 1) {
        int t = (threadIdx.x >= off) ? lds[threadIdx.x - off] : 0;
        __syncthreads();
        lds[threadIdx.x] += t;
        __syncthreads();
    }
    int run = blockOffsets[blockIdx.x] + lds[threadIdx.x] - s;
#pragma unroll
    for (int j = 0; j < 4; j++) {
        int i = base + j;
        if (i < n) {
            offsets[i] = run;
            cursor[i] = run;
            run += v[j];
        }
    }
}

__global__ void dinv_kernel(const int* __restrict__ counts, float* __restrict__ dinv, int n) {
    int i = blockIdx.x * blockDim.x + threadIdx.x;
    if (i < n) dinv[i] = 1.0f / sqrtf((float)(counts[i] + 1));  // deg = in_count + self-loop
}

__global__ void scatter_kernel(const int* __restrict__ src, const int* __restrict__ dst,
                               int* __restrict__ cursor, int* __restrict__ sorted_src, int E) {
    int stride = gridDim.x * blockDim.x;
    for (int e = blockIdx.x * blockDim.x + threadIdx.x; e < E; e += stride) {
        int d = dst[e];
        int p = atomicAdd(&cursor[d], 1);
        sorted_src[p] = src[e];
    }
}

// ---------------- per-layer compute ----------------

// Y[row][c] = (sum_k X[row][k] * W[k][c]) * dinv[row]
__global__ void gemm_scale(const float* __restrict__ X, const float* __restrict__ W,
                           const float* __restrict__ dinv, float* __restrict__ Y, int n) {
    __shared__ float Wl[64][65];
    __shared__ float Xl[16][64];
    int tid = threadIdx.x;
#pragma unroll
    for (int i = 0; i < 16; i++) {
        int idx = tid + i * 256;
        Wl[idx >> 6][idx & 63] = W[idx];
    }
    int row0 = blockIdx.x * 16;
#pragma unroll
    for (int i = 0; i < 4; i++) {
        int idx = tid + i * 256;
        int r = idx >> 6, c = idx & 63;
        int row = row0 + r;
        Xl[r][c] = (row < n) ? X[(size_t)row * DF + c] : 0.f;
    }
    __syncthreads();
    int c = tid & 63;
    int r0 = tid >> 6;
#pragma unroll
    for (int rr = 0; rr < 4; rr++) {
        int lr = r0 + rr * 4;
        int row = row0 + lr;
        float acc = 0.f;
#pragma unroll
        for (int k = 0; k < 64; k++) acc += Xl[lr][k] * Wl[k][c];
        if (row < n) Y[(size_t)row * DF + c] = acc * dinv[row];
    }
}

// H[i][lane] = relu(dinv[i]*(Y[i][lane] + sum_{in-edges} Y[src][lane]) + b[lane])
__global__ void aggregate_kernel(const float* __restrict__ Y, const int* __restrict__ sorted_src,
                                 const int* __restrict__ offsets, const float* __restrict__ dinv,
                                 const float* __restrict__ bias, float* __restrict__ H, int n) {
    int node = blockIdx.x * 4 + (threadIdx.x >> 6);
    if (node >= n) return;
    int lane = threadIdx.x & 63;
    int s = offsets[node], e = offsets[node + 1];
    float acc = Y[(size_t)node * DF + lane];
    for (int i = s; i < e; i++) {
        int sv = sorted_src[i];
        acc += Y[(size_t)sv * DF + lane];
    }
    float v = dinv[node] * acc + bias[lane];
    H[(size_t)node * DF + lane] = fmaxf(v, 0.f);
}

// ---------------- pooling + head ----------------

__global__ void pool_kernel(const float* __restrict__ H, const int* __restrict__ batch,
                            float* __restrict__ sums, int* __restrict__ cnts, int n) {
    int gw = (blockIdx.x * blockDim.x + threadIdx.x) >> 6;
    int lane = threadIdx.x & 63;
    int start = gw * 256;
    if (start >= n) return;
    int end = min(start + 256, n);
    int cur = batch[start];
    float acc = 0.f;
    int run = 0;
    for (int i = start; i < end; i++) {
        int g = batch[i];
        if (g != cur) {
            atomicAdd(&sums[cur * DF + lane], acc);
            if (lane == 0) atomicAdd(&cnts[cur], run);
            acc = 0.f;
            run = 0;
            cur = g;
        }
        acc += H[(size_t)i * DF + lane];
        run++;
    }
    atomicAdd(&sums[cur * DF + lane], acc);
    if (lane == 0) atomicAdd(&cnts[cur], run);
}

__global__ void final_kernel(const float* __restrict__ sums, const int* __restrict__ cnts,
                             const float* __restrict__ Wp, const float* __restrict__ bp,
                             float* __restrict__ out) {
    int g = blockIdx.x, j = threadIdx.x;
    __shared__ float hg[64];
    float c = fmaxf((float)cnts[g], 1.f);
    hg[j] = sums[g * DF + j] / c;
    __syncthreads();
    float acc = bp[j];
#pragma unroll
    for (int k = 0; k < 64; k++) acc += hg[k] * Wp[k * DF + j];
    out[g * DF + j] = acc;
}

// ---------------- launch ----------------

extern "C" void kernel_launch(void* const* d_in, const int* in_sizes, int n_in,
                              void* d_out, int out_size, void* d_ws, size_t ws_size,
                              hipStream_t stream) {
    const float* x     = (const float*)d_in[0];
    const int*   ei    = (const int*)d_in[1];
    const int*   batch = (const int*)d_in[2];
    const float* W1    = (const float*)d_in[3];
    const float* b1    = (const float*)d_in[4];
    const float* W2    = (const float*)d_in[5];
    const float* b2    = (const float*)d_in[6];
    const float* Wp    = (const float*)d_in[7];
    const float* bp    = (const float*)d_in[8];

    int N = in_sizes[0] / DF;
    int E = in_sizes[1] / 2;
    const int* src = ei;
    const int* dst = ei + E;

    char* ws = (char*)d_ws;
    auto alloc = [&](size_t bytes) {
        void* p = (void*)ws;
        ws += (bytes + 255) / 256 * 256;
        return p;
    };
    float* dinv    = (float*)alloc((size_t)N * 4);
    int*   counts  = (int*)alloc((size_t)N * 4);
    int*   offsets = (int*)alloc((size_t)(N + 1) * 4);
    int*   cursor  = (int*)alloc((size_t)N * 4);
    int*   bsums   = (int*)alloc(1024 * 4);
    int*   boffs   = (int*)alloc(1024 * 4);
    int*   ssrc    = (int*)alloc((size_t)E * 4);
    float* y       = (float*)alloc((size_t)N * DF * 4);
    float* h       = (float*)alloc((size_t)N * DF * 4);
    float* psums   = (float*)alloc(64 * DF * 4);   // 16 KB, 256-aligned
    int*   pcnt    = (int*)alloc(64 * 4);

    hipMemsetAsync(counts, 0, (size_t)N * 4, stream);
    hipMemsetAsync(psums, 0, 64 * DF * 4 + 256, stream);  // sums + cnts (contiguous)

    int B = (N + 1023) / 1024;
    hist_kernel<<<2048, 256, 0, stream>>>(dst, counts, E);
    scan_a<<<B, 256, 0, stream>>>(counts, bsums, N);
    scan_b<<<1, 256, 0, stream>>>(bsums, boffs, offsets + N, B);
    scan_c<<<B, 256, 0, stream>>>(counts, boffs, offsets, cursor, N);
    dinv_kernel<<<(N + 255) / 256, 256, 0, stream>>>(counts, dinv, N);
    scatter_kernel<<<2048, 256, 0, stream>>>(src, dst, cursor, ssrc, E);

    gemm_scale<<<(N + 15) / 16, 256, 0, stream>>>(x, W1, dinv, y, N);
    aggregate_kernel<<<(N + 3) / 4, 256, 0, stream>>>(y, ssrc, offsets, dinv, b1, h, N);
    gemm_scale<<<(N + 15) / 16, 256, 0, stream>>>(h, W2, dinv, y, N);
    aggregate_kernel<<<(N + 3) / 4, 256, 0, stream>>>(y, ssrc, offsets, dinv, b2, h, N);

    int waves = (N + 255) / 256;
    pool_kernel<<<(waves + 3) / 4, 256, 0, stream>>>(h, batch, psums, pcnt, N);
    final_kernel<<<64, 64, 0, stream>>>(psums, pcnt, Wp, bp, (float*)d_out);
}

// Round 2
// 488.690 us; speedup vs baseline: 1.5335x; 1.5335x over previous
//
#include <hip/hip_runtime.h>

// TemporalGCN: 2x GCNConv(64->64) + relu, global_mean_pool(64 graphs), linear 64->64.
// CSR-by-dst build (counting sort) -> y = (x@W)*dinv -> per-node gather-sum.
// R1: float4 + 4-edges-in-flight aggregation, vectorized GEMM/hist/scatter/pool.

#define DF 64

// ---------------- CSR build ----------------

__global__ void hist_kernel(const int* __restrict__ dst, const int4* __restrict__ dst4,
                            int* __restrict__ counts, int E, int nq) {
    int stride = gridDim.x * blockDim.x;
    for (int e = blockIdx.x * blockDim.x + threadIdx.x; e < nq; e += stride) {
        int4 d = dst4[e];
        atomicAdd(&counts[d.x], 1);
        atomicAdd(&counts[d.y], 1);
        atomicAdd(&counts[d.z], 1);
        atomicAdd(&counts[d.w], 1);
    }
    for (int e = 4 * nq + blockIdx.x * blockDim.x + threadIdx.x; e < E; e += stride)
        atomicAdd(&counts[dst[e]], 1);
}

__global__ void scan_a(const int* __restrict__ counts, int* __restrict__ blockSums, int n) {
    __shared__ int lds[256];
    int base = blockIdx.x * 1024 + threadIdx.x * 4;
    int s = 0;
#pragma unroll
    for (int j = 0; j < 4; j++) {
        int i = base + j;
        if (i < n) s += counts[i];
    }
    lds[threadIdx.x] = s;
    __syncthreads();
    for (int off = 128; off > 0; off >>= 1) {
        if (threadIdx.x < off) lds[threadIdx.x] += lds[threadIdx.x + off];
        __syncthreads();
    }
    if (threadIdx.x == 0) blockSums[blockIdx.x] = lds[0];
}

// single block; B <= 256
__global__ void scan_b(const int* __restrict__ blockSums, int* __restrict__ blockOffsets,
                       int* __restrict__ offsets_end, int B) {
    __shared__ int lds[256];
    int v = (threadIdx.x < B) ? blockSums[threadIdx.x] : 0;
    lds[threadIdx.x] = v;
    __syncthreads();
    for (int off = 1; off < 256; off <<= 1) {
        int t = (threadIdx.x >= off) ? lds[threadIdx.x - off] : 0;
        __syncthreads();
        lds[threadIdx.x] += t;
        __syncthreads();
    }
    if (threadIdx.x < B) blockOffsets[threadIdx.x] = lds[threadIdx.x] - v;
    if (threadIdx.x == 255) offsets_end[0] = lds[255];  // total (= E)
}

__global__ void scan_c(const int* __restrict__ counts, const int* __restrict__ blockOffsets,
                       int* __restrict__ offsets, int* __restrict__ cursor, int n) {
    __shared__ int lds[256];
    int base = blockIdx.x * 1024 + threadIdx.x * 4;
    int v[4];
    int s = 0;
#pragma unroll
    for (int j = 0; j < 4; j++) {
        int i = base + j;
        v[j] = (i < n) ? counts[i] : 0;
        s += v[j];
    }
    lds[threadIdx.x] = s;
    __syncthreads();
    for (int off = 1; off < 256; off <<= 1) {
        int t = (threadIdx.x >= off) ? lds[threadIdx.x - off] : 0;
        __syncthreads();
        lds[threadIdx.x] += t;
        __syncthreads();
    }
    int run = blockOffsets[blockIdx.x] + lds[threadIdx.x] - s;
#pragma unroll
    for (int j = 0; j < 4; j++) {
        int i = base + j;
        if (i < n) {
            offsets[i] = run;
            cursor[i] = run;
            run += v[j];
        }
    }
}

__global__ void dinv_kernel(const int* __restrict__ counts, float* __restrict__ dinv, int n) {
    int i = blockIdx.x * blockDim.x + threadIdx.x;
    if (i < n) dinv[i] = 1.0f / sqrtf((float)(counts[i] + 1));  // deg = in_count + self-loop
}

__global__ void scatter_kernel(const int* __restrict__ src, const int* __restrict__ dst,
                               const int4* __restrict__ src4, const int4* __restrict__ dst4,
                               int* __restrict__ cursor, int* __restrict__ sorted_src,
                               int E, int nq) {
    int stride = gridDim.x * blockDim.x;
    for (int e = blockIdx.x * blockDim.x + threadIdx.x; e < nq; e += stride) {
        int4 s = src4[e];
        int4 d = dst4[e];
        int p0 = atomicAdd(&cursor[d.x], 1);
        int p1 = atomicAdd(&cursor[d.y], 1);
        int p2 = atomicAdd(&cursor[d.z], 1);
        int p3 = atomicAdd(&cursor[d.w], 1);
        sorted_src[p0] = s.x;
        sorted_src[p1] = s.y;
        sorted_src[p2] = s.z;
        sorted_src[p3] = s.w;
    }
    for (int e = 4 * nq + blockIdx.x * blockDim.x + threadIdx.x; e < E; e += stride) {
        int d = dst[e];
        int p = atomicAdd(&cursor[d], 1);
        sorted_src[p] = src[e];
    }
}

// ---------------- per-layer compute ----------------

// Y[row][c] = (sum_k X[row][k] * W[k][c]) * dinv[row]; float4 per thread.
__global__ void gemm_scale(const float4* __restrict__ X4, const float4* __restrict__ W4,
                           const float* __restrict__ dinv, float4* __restrict__ Y4, int n) {
    __shared__ float4 Wl4[64][16];   // [k][c4]
    __shared__ float Xl[16][68];     // padded: stride 68 -> conflict-free broadcast
    int tid = threadIdx.x;
    float4* Wf = &Wl4[0][0];
#pragma unroll
    for (int i = 0; i < 4; i++) {
        int idx = tid + i * 256;     // idx = k*16 + c4
        Wf[idx] = W4[idx];
    }
    int row0 = blockIdx.x * 16;
    int r = tid >> 4, c4 = tid & 15;
    {
        int row = row0 + r;
        float4 v = (row < n) ? X4[(size_t)row * 16 + c4] : float4{0.f, 0.f, 0.f, 0.f};
        Xl[r][c4 * 4 + 0] = v.x;
        Xl[r][c4 * 4 + 1] = v.y;
        Xl[r][c4 * 4 + 2] = v.z;
        Xl[r][c4 * 4 + 3] = v.w;
    }
    __syncthreads();
    float ax = 0.f, ay = 0.f, az = 0.f, aw = 0.f;
#pragma unroll
    for (int k = 0; k < 64; k++) {
        float xv = Xl[r][k];
        float4 w = Wl4[k][c4];
        ax += xv * w.x;
        ay += xv * w.y;
        az += xv * w.z;
        aw += xv * w.w;
    }
    int row = row0 + r;
    if (row < n) {
        float dv = dinv[row];
        Y4[(size_t)row * 16 + c4] = float4{ax * dv, ay * dv, az * dv, aw * dv};
    }
}

// H[i][:] = relu(dinv[i]*(Y[i][:] + sum_{in-edges} Y[src][:]) + b)
// One wave per node; 4 lane-groups of 16 handle 4 edges concurrently, float4/lane.
__global__ void aggregate_kernel(const float4* __restrict__ Y4, const int* __restrict__ sorted_src,
                                 const int* __restrict__ offsets, const float* __restrict__ dinv,
                                 const float4* __restrict__ bias4, float4* __restrict__ H4, int n) {
    int node = blockIdx.x * 4 + (threadIdx.x >> 6);
    if (node >= n) return;
    int lane = threadIdx.x & 63;
    int g = lane >> 4, q = lane & 15;
    int s = offsets[node], e = offsets[node + 1];
    float ax = 0.f, ay = 0.f, az = 0.f, aw = 0.f;
    float bx = 0.f, by = 0.f, bz = 0.f, bw = 0.f;
    int i = s + g;
    for (; i + 4 < e; i += 8) {
        int sv0 = sorted_src[i];
        int sv1 = sorted_src[i + 4];
        float4 v0 = Y4[(size_t)sv0 * 16 + q];
        float4 v1 = Y4[(size_t)sv1 * 16 + q];
        ax += v0.x; ay += v0.y; az += v0.z; aw += v0.w;
        bx += v1.x; by += v1.y; bz += v1.z; bw += v1.w;
    }
    if (i < e) {
        int sv = sorted_src[i];
        float4 v = Y4[(size_t)sv * 16 + q];
        ax += v.x; ay += v.y; az += v.z; aw += v.w;
    }
    ax += bx; ay += by; az += bz; aw += bw;
    // reduce across the 4 lane-groups (xor 16, 32)
#pragma unroll
    for (int m = 16; m <= 32; m <<= 1) {
        ax += __shfl_xor(ax, m);
        ay += __shfl_xor(ay, m);
        az += __shfl_xor(az, m);
        aw += __shfl_xor(aw, m);
    }
    float4 self = Y4[(size_t)node * 16 + q];
    float dv = dinv[node];
    float4 b = bias4[q];
    float4 r;
    r.x = fmaxf(dv * (ax + self.x) + b.x, 0.f);
    r.y = fmaxf(dv * (ay + self.y) + b.y, 0.f);
    r.z = fmaxf(dv * (az + self.z) + b.z, 0.f);
    r.w = fmaxf(dv * (aw + self.w) + b.w, 0.f);
    if (g == 0) H4[(size_t)node * 16 + q] = r;
}

// ---------------- pooling + head ----------------

// Each wave owns a 256-row run; 4 lane-groups take rows i, i+1, i+2, i+3 (step 4).
__global__ void pool_kernel(const float4* __restrict__ H4, const int* __restrict__ batch,
                            float* __restrict__ sums, int* __restrict__ cnts, int n) {
    int gw = (blockIdx.x * blockDim.x + threadIdx.x) >> 6;
    int lane = threadIdx.x & 63;
    int g = lane >> 4, q = lane & 15;
    int start = gw * 256;
    if (start >= n) return;
    int end = min(start + 256, n);
    float ax = 0.f, ay = 0.f, az = 0.f, aw = 0.f;
    int cur = -1, run = 0;
    for (int i = start + g; i < end; i += 4) {
        int b = batch[i];
        if (b != cur) {
            if (run > 0) {
                atomicAdd(&sums[cur * DF + q * 4 + 0], ax);
                atomicAdd(&sums[cur * DF + q * 4 + 1], ay);
                atomicAdd(&sums[cur * DF + q * 4 + 2], az);
                atomicAdd(&sums[cur * DF + q * 4 + 3], aw);
                if (q == 0) atomicAdd(&cnts[cur], run);
            }
            cur = b; run = 0;
            ax = ay = az = aw = 0.f;
        }
        float4 v = H4[(size_t)i * 16 + q];
        ax += v.x; ay += v.y; az += v.z; aw += v.w;
        run++;
    }
    if (run > 0) {
        atomicAdd(&sums[cur * DF + q * 4 + 0], ax);
        atomicAdd(&sums[cur * DF + q * 4 + 1], ay);
        atomicAdd(&sums[cur * DF + q * 4 + 2], az);
        atomicAdd(&sums[cur * DF + q * 4 + 3], aw);
        if (q == 0) atomicAdd(&cnts[cur], run);
    }
}

__global__ void final_kernel(const float* __restrict__ sums, const int* __restrict__ cnts,
                             const float* __restrict__ Wp, const float* __restrict__ bp,
                             float* __restrict__ out) {
    int g = blockIdx.x, j = threadIdx.x;
    __shared__ float hg[64];
    float c = fmaxf((float)cnts[g], 1.f);
    hg[j] = sums[g * DF + j] / c;
    __syncthreads();
    float acc = bp[j];
#pragma unroll
    for (int k = 0; k < 64; k++) acc += hg[k] * Wp[k * DF + j];
    out[g * DF + j] = acc;
}

// ---------------- launch ----------------

extern "C" void kernel_launch(void* const* d_in, const int* in_sizes, int n_in,
                              void* d_out, int out_size, void* d_ws, size_t ws_size,
                              hipStream_t stream) {
    const float* x     = (const float*)d_in[0];
    const int*   ei    = (const int*)d_in[1];
    const int*   batch = (const int*)d_in[2];
    const float* W1    = (const float*)d_in[3];
    const float* b1    = (const float*)d_in[4];
    const float* W2    = (const float*)d_in[5];
    const float* b2    = (const float*)d_in[6];
    const float* Wp    = (const float*)d_in[7];
    const float* bp    = (const float*)d_in[8];

    int N = in_sizes[0] / DF;
    int E = in_sizes[1] / 2;
    const int* src = ei;
    const int* dst = ei + E;
    // int4 fast path only if both src/dst 16B-aligned (dst offset = E*4 bytes)
    int nq = ((E & 3) == 0 && (((uintptr_t)ei & 15) == 0)) ? (E >> 2) : 0;

    char* ws = (char*)d_ws;
    auto alloc = [&](size_t bytes) {
        void* p = (void*)ws;
        ws += (bytes + 255) / 256 * 256;
        return p;
    };
    float* dinv    = (float*)alloc((size_t)N * 4);
    int*   counts  = (int*)alloc((size_t)N * 4);
    int*   offsets = (int*)alloc((size_t)(N + 1) * 4);
    int*   cursor  = (int*)alloc((size_t)N * 4);
    int*   bsums   = (int*)alloc(1024 * 4);
    int*   boffs   = (int*)alloc(1024 * 4);
    int*   ssrc    = (int*)alloc((size_t)E * 4);
    float* y       = (float*)alloc((size_t)N * DF * 4);
    float* h       = (float*)alloc((size_t)N * DF * 4);
    float* psums   = (float*)alloc(64 * DF * 4);   // 16 KB, 256-aligned
    int*   pcnt    = (int*)alloc(64 * 4);

    hipMemsetAsync(counts, 0, (size_t)N * 4, stream);
    hipMemsetAsync(psums, 0, 64 * DF * 4 + 256, stream);  // sums + cnts (contiguous)

    int B = (N + 1023) / 1024;
    int histBlocks = min(2048, (max(nq, 1) + 255) / 256);
    hist_kernel<<<histBlocks, 256, 0, stream>>>(dst, (const int4*)dst, counts, E, nq);
    scan_a<<<B, 256, 0, stream>>>(counts, bsums, N);
    scan_b<<<1, 256, 0, stream>>>(bsums, boffs, offsets + N, B);
    scan_c<<<B, 256, 0, stream>>>(counts, boffs, offsets, cursor, N);
    dinv_kernel<<<(N + 255) / 256, 256, 0, stream>>>(counts, dinv, N);
    scatter_kernel<<<histBlocks, 256, 0, stream>>>(src, dst, (const int4*)src, (const int4*)dst,
                                                   cursor, ssrc, E, nq);

    gemm_scale<<<(N + 15) / 16, 256, 0, stream>>>((const float4*)x, (const float4*)W1, dinv,
                                                  (float4*)y, N);
    aggregate_kernel<<<(N + 3) / 4, 256, 0, stream>>>((const float4*)y, ssrc, offsets, dinv,
                                                      (const float4*)b1, (float4*)h, N);
    gemm_scale<<<(N + 15) / 16, 256, 0, stream>>>((const float4*)h, (const float4*)W2, dinv,
                                                  (float4*)y, N);
    aggregate_kernel<<<(N + 3) / 4, 256, 0, stream>>>((const float4*)y, ssrc, offsets, dinv,
                                                      (const float4*)b2, (float4*)h, N);

    int waves = (N + 255) / 256;
    pool_kernel<<<(waves + 3) / 4, 256, 0, stream>>>((const float4*)h, batch, psums, pcnt, N);
    final_kernel<<<64, 64, 0, stream>>>(psums, pcnt, Wp, bp, (float*)d_out);
}

// Round 3
// 437.468 us; speedup vs baseline: 1.7130x; 1.1171x over previous
//
#include <hip/hip_runtime.h>

// TemporalGCN: 2x GCNConv(64->64) + relu, global_mean_pool(64 graphs), linear 64->64.
// CSR-by-dst build (counting sort) -> y = (x@W)*dinv -> per-node gather-sum.
// R2: dst-space sharding (8 interleaved 4096-node stripes) for hist/scatter so
// random writes/atomics stay in an ~0.8MB L2-resident window per shard.
// Aggregate unrolled x4 (16 gathers in flight per wave).

#define DF 64
#define SHARD_SHIFT 12   // 4096-node stripes, stripe id & 7 = shard

// ---------------- CSR build ----------------

__global__ void hist_kernel(const int* __restrict__ dst, const int4* __restrict__ dst4,
                            int* __restrict__ counts, int E, int nq) {
    int shard = blockIdx.x & 7;
    int stride = (gridDim.x >> 3) * blockDim.x;
    int start = (blockIdx.x >> 3) * blockDim.x + threadIdx.x;
    for (int e = start; e < nq; e += stride) {
        int4 d = dst4[e];
        if (((d.x >> SHARD_SHIFT) & 7) == shard) atomicAdd(&counts[d.x], 1);
        if (((d.y >> SHARD_SHIFT) & 7) == shard) atomicAdd(&counts[d.y], 1);
        if (((d.z >> SHARD_SHIFT) & 7) == shard) atomicAdd(&counts[d.z], 1);
        if (((d.w >> SHARD_SHIFT) & 7) == shard) atomicAdd(&counts[d.w], 1);
    }
    for (int e = 4 * nq + start; e < E; e += stride) {
        int d = dst[e];
        if (((d >> SHARD_SHIFT) & 7) == shard) atomicAdd(&counts[d], 1);
    }
}

__global__ void scan_a(const int* __restrict__ counts, int* __restrict__ blockSums, int n) {
    __shared__ int lds[256];
    int base = blockIdx.x * 1024 + threadIdx.x * 4;
    int s = 0;
#pragma unroll
    for (int j = 0; j < 4; j++) {
        int i = base + j;
        if (i < n) s += counts[i];
    }
    lds[threadIdx.x] = s;
    __syncthreads();
    for (int off = 128; off > 0; off >>= 1) {
        if (threadIdx.x < off) lds[threadIdx.x] += lds[threadIdx.x + off];
        __syncthreads();
    }
    if (threadIdx.x == 0) blockSums[blockIdx.x] = lds[0];
}

// single block; B <= 256
__global__ void scan_b(const int* __restrict__ blockSums, int* __restrict__ blockOffsets,
                       int* __restrict__ offsets_end, int B) {
    __shared__ int lds[256];
    int v = (threadIdx.x < B) ? blockSums[threadIdx.x] : 0;
    lds[threadIdx.x] = v;
    __syncthreads();
    for (int off = 1; off < 256; off <<= 1) {
        int t = (threadIdx.x >= off) ? lds[threadIdx.x - off] : 0;
        __syncthreads();
        lds[threadIdx.x] += t;
        __syncthreads();
    }
    if (threadIdx.x < B) blockOffsets[threadIdx.x] = lds[threadIdx.x] - v;
    if (threadIdx.x == 255) offsets_end[0] = lds[255];  // total (= E)
}

__global__ void scan_c(const int* __restrict__ counts, const int* __restrict__ blockOffsets,
                       int* __restrict__ offsets, int* __restrict__ cursor, int n) {
    __shared__ int lds[256];
    int base = blockIdx.x * 1024 + threadIdx.x * 4;
    int v[4];
    int s = 0;
#pragma unroll
    for (int j = 0; j < 4; j++) {
        int i = base + j;
        v[j] = (i < n) ? counts[i] : 0;
        s += v[j];
    }
    lds[threadIdx.x] = s;
    __syncthreads();
    for (int off = 1; off < 256; off <<= 1) {
        int t = (threadIdx.x >= off) ? lds[threadIdx.x - off] : 0;
        __syncthreads();
        lds[threadIdx.x] += t;
        __syncthreads();
    }
    int run = blockOffsets[blockIdx.x] + lds[threadIdx.x] - s;
#pragma unroll
    for (int j = 0; j < 4; j++) {
        int i = base + j;
        if (i < n) {
            offsets[i] = run;
            cursor[i] = run;
            run += v[j];
        }
    }
}

__global__ void dinv_kernel(const int* __restrict__ counts, float* __restrict__ dinv, int n) {
    int i = blockIdx.x * blockDim.x + threadIdx.x;
    if (i < n) dinv[i] = 1.0f / sqrtf((float)(counts[i] + 1));  // deg = in_count + self-loop
}

__global__ void scatter_kernel(const int* __restrict__ src, const int* __restrict__ dst,
                               const int4* __restrict__ src4, const int4* __restrict__ dst4,
                               int* __restrict__ cursor, int* __restrict__ sorted_src,
                               int E, int nq) {
    int shard = blockIdx.x & 7;
    int stride = (gridDim.x >> 3) * blockDim.x;
    int start = (blockIdx.x >> 3) * blockDim.x + threadIdx.x;
    for (int e = start; e < nq; e += stride) {
        int4 d = dst4[e];
        int m0 = ((d.x >> SHARD_SHIFT) & 7) == shard;
        int m1 = ((d.y >> SHARD_SHIFT) & 7) == shard;
        int m2 = ((d.z >> SHARD_SHIFT) & 7) == shard;
        int m3 = ((d.w >> SHARD_SHIFT) & 7) == shard;
        if (m0 | m1 | m2 | m3) {
            int4 s = src4[e];
            if (m0) sorted_src[atomicAdd(&cursor[d.x], 1)] = s.x;
            if (m1) sorted_src[atomicAdd(&cursor[d.y], 1)] = s.y;
            if (m2) sorted_src[atomicAdd(&cursor[d.z], 1)] = s.z;
            if (m3) sorted_src[atomicAdd(&cursor[d.w], 1)] = s.w;
        }
    }
    for (int e = 4 * nq + start; e < E; e += stride) {
        int d = dst[e];
        if (((d >> SHARD_SHIFT) & 7) == shard)
            sorted_src[atomicAdd(&cursor[d], 1)] = src[e];
    }
}

// ---------------- per-layer compute ----------------

// Y[row][c] = (sum_k X[row][k] * W[k][c]) * dinv[row]; float4 per thread.
__global__ void gemm_scale(const float4* __restrict__ X4, const float4* __restrict__ W4,
                           const float* __restrict__ dinv, float4* __restrict__ Y4, int n) {
    __shared__ float4 Wl4[64][16];   // [k][c4]
    __shared__ float Xl[16][68];     // padded: stride 68 -> conflict-free broadcast
    int tid = threadIdx.x;
    float4* Wf = &Wl4[0][0];
#pragma unroll
    for (int i = 0; i < 4; i++) {
        int idx = tid + i * 256;     // idx = k*16 + c4
        Wf[idx] = W4[idx];
    }
    int row0 = blockIdx.x * 16;
    int r = tid >> 4, c4 = tid & 15;
    {
        int row = row0 + r;
        float4 v = (row < n) ? X4[(size_t)row * 16 + c4] : float4{0.f, 0.f, 0.f, 0.f};
        Xl[r][c4 * 4 + 0] = v.x;
        Xl[r][c4 * 4 + 1] = v.y;
        Xl[r][c4 * 4 + 2] = v.z;
        Xl[r][c4 * 4 + 3] = v.w;
    }
    __syncthreads();
    float ax = 0.f, ay = 0.f, az = 0.f, aw = 0.f;
#pragma unroll
    for (int k = 0; k < 64; k++) {
        float xv = Xl[r][k];
        float4 w = Wl4[k][c4];
        ax += xv * w.x;
        ay += xv * w.y;
        az += xv * w.z;
        aw += xv * w.w;
    }
    int row = row0 + r;
    if (row < n) {
        float dv = dinv[row];
        Y4[(size_t)row * 16 + c4] = float4{ax * dv, ay * dv, az * dv, aw * dv};
    }
}

// H[i][:] = relu(dinv[i]*(Y[i][:] + sum_{in-edges} Y[src][:]) + b)
// One wave per node; 4 lane-groups of 16 handle 4 edges concurrently, float4/lane,
// unrolled x4 -> up to 16 gathers in flight per wave.
__global__ void aggregate_kernel(const float4* __restrict__ Y4, const int* __restrict__ sorted_src,
                                 const int* __restrict__ offsets, const float* __restrict__ dinv,
                                 const float4* __restrict__ bias4, float4* __restrict__ H4, int n) {
    int node = blockIdx.x * 4 + (threadIdx.x >> 6);
    if (node >= n) return;
    int lane = threadIdx.x & 63;
    int g = lane >> 4, q = lane & 15;
    int s = offsets[node], e = offsets[node + 1];
    float ax = 0.f, ay = 0.f, az = 0.f, aw = 0.f;
    float bx = 0.f, by = 0.f, bz = 0.f, bw = 0.f;
    float cx = 0.f, cy = 0.f, cz = 0.f, cw = 0.f;
    float dx = 0.f, dy = 0.f, dz = 0.f, dw = 0.f;
    int i = s + g;
    for (; i + 12 < e; i += 16) {
        int s0 = sorted_src[i];
        int s1 = sorted_src[i + 4];
        int s2 = sorted_src[i + 8];
        int s3 = sorted_src[i + 12];
        float4 v0 = Y4[(size_t)s0 * 16 + q];
        float4 v1 = Y4[(size_t)s1 * 16 + q];
        float4 v2 = Y4[(size_t)s2 * 16 + q];
        float4 v3 = Y4[(size_t)s3 * 16 + q];
        ax += v0.x; ay += v0.y; az += v0.z; aw += v0.w;
        bx += v1.x; by += v1.y; bz += v1.z; bw += v1.w;
        cx += v2.x; cy += v2.y; cz += v2.z; cw += v2.w;
        dx += v3.x; dy += v3.y; dz += v3.z; dw += v3.w;
    }
    for (; i < e; i += 4) {
        int sv = sorted_src[i];
        float4 v = Y4[(size_t)sv * 16 + q];
        ax += v.x; ay += v.y; az += v.z; aw += v.w;
    }
    ax += bx + cx + dx;
    ay += by + cy + dy;
    az += bz + cz + dz;
    aw += bw + cw + dw;
    // reduce across the 4 lane-groups (xor 16, 32)
#pragma unroll
    for (int m = 16; m <= 32; m <<= 1) {
        ax += __shfl_xor(ax, m);
        ay += __shfl_xor(ay, m);
        az += __shfl_xor(az, m);
        aw += __shfl_xor(aw, m);
    }
    float4 self = Y4[(size_t)node * 16 + q];
    float dv = dinv[node];
    float4 b = bias4[q];
    float4 r;
    r.x = fmaxf(dv * (ax + self.x) + b.x, 0.f);
    r.y = fmaxf(dv * (ay + self.y) + b.y, 0.f);
    r.z = fmaxf(dv * (az + self.z) + b.z, 0.f);
    r.w = fmaxf(dv * (aw + self.w) + b.w, 0.f);
    if (g == 0) H4[(size_t)node * 16 + q] = r;
}

// ---------------- pooling + head ----------------

// Each wave owns a 256-row run; 4 lane-groups take rows i, i+1, i+2, i+3 (step 4).
__global__ void pool_kernel(const float4* __restrict__ H4, const int* __restrict__ batch,
                            float* __restrict__ sums, int* __restrict__ cnts, int n) {
    int gw = (blockIdx.x * blockDim.x + threadIdx.x) >> 6;
    int lane = threadIdx.x & 63;
    int g = lane >> 4, q = lane & 15;
    int start = gw * 256;
    if (start >= n) return;
    int end = min(start + 256, n);
    float ax = 0.f, ay = 0.f, az = 0.f, aw = 0.f;
    int cur = -1, run = 0;
    for (int i = start + g; i < end; i += 4) {
        int b = batch[i];
        if (b != cur) {
            if (run > 0) {
                atomicAdd(&sums[cur * DF + q * 4 + 0], ax);
                atomicAdd(&sums[cur * DF + q * 4 + 1], ay);
                atomicAdd(&sums[cur * DF + q * 4 + 2], az);
                atomicAdd(&sums[cur * DF + q * 4 + 3], aw);
                if (q == 0) atomicAdd(&cnts[cur], run);
            }
            cur = b; run = 0;
            ax = ay = az = aw = 0.f;
        }
        float4 v = H4[(size_t)i * 16 + q];
        ax += v.x; ay += v.y; az += v.z; aw += v.w;
        run++;
    }
    if (run > 0) {
        atomicAdd(&sums[cur * DF + q * 4 + 0], ax);
        atomicAdd(&sums[cur * DF + q * 4 + 1], ay);
        atomicAdd(&sums[cur * DF + q * 4 + 2], az);
        atomicAdd(&sums[cur * DF + q * 4 + 3], aw);
        if (q == 0) atomicAdd(&cnts[cur], run);
    }
}

__global__ void final_kernel(const float* __restrict__ sums, const int* __restrict__ cnts,
                             const float* __restrict__ Wp, const float* __restrict__ bp,
                             float* __restrict__ out) {
    int g = blockIdx.x, j = threadIdx.x;
    __shared__ float hg[64];
    float c = fmaxf((float)cnts[g], 1.f);
    hg[j] = sums[g * DF + j] / c;
    __syncthreads();
    float acc = bp[j];
#pragma unroll
    for (int k = 0; k < 64; k++) acc += hg[k] * Wp[k * DF + j];
    out[g * DF + j] = acc;
}

// ---------------- launch ----------------

extern "C" void kernel_launch(void* const* d_in, const int* in_sizes, int n_in,
                              void* d_out, int out_size, void* d_ws, size_t ws_size,
                              hipStream_t stream) {
    const float* x     = (const float*)d_in[0];
    const int*   ei    = (const int*)d_in[1];
    const int*   batch = (const int*)d_in[2];
    const float* W1    = (const float*)d_in[3];
    const float* b1    = (const float*)d_in[4];
    const float* W2    = (const float*)d_in[5];
    const float* b2    = (const float*)d_in[6];
    const float* Wp    = (const float*)d_in[7];
    const float* bp    = (const float*)d_in[8];

    int N = in_sizes[0] / DF;
    int E = in_sizes[1] / 2;
    const int* src = ei;
    const int* dst = ei + E;
    // int4 fast path only if both src/dst 16B-aligned (dst offset = E*4 bytes)
    int nq = ((E & 3) == 0 && (((uintptr_t)ei & 15) == 0)) ? (E >> 2) : 0;

    char* ws = (char*)d_ws;
    auto alloc = [&](size_t bytes) {
        void* p = (void*)ws;
        ws += (bytes + 255) / 256 * 256;
        return p;
    };
    float* dinv    = (float*)alloc((size_t)N * 4);
    int*   counts  = (int*)alloc((size_t)N * 4);
    int*   offsets = (int*)alloc((size_t)(N + 1) * 4);
    int*   cursor  = (int*)alloc((size_t)N * 4);
    int*   bsums   = (int*)alloc(1024 * 4);
    int*   boffs   = (int*)alloc(1024 * 4);
    int*   ssrc    = (int*)alloc((size_t)E * 4);
    float* y       = (float*)alloc((size_t)N * DF * 4);
    float* h       = (float*)alloc((size_t)N * DF * 4);
    float* psums   = (float*)alloc(64 * DF * 4);   // 16 KB, 256-aligned
    int*   pcnt    = (int*)alloc(64 * 4);

    hipMemsetAsync(counts, 0, (size_t)N * 4, stream);
    hipMemsetAsync(psums, 0, 64 * DF * 4 + 256, stream);  // sums + cnts (contiguous)

    int B = (N + 1023) / 1024;
    hist_kernel<<<2048, 256, 0, stream>>>(dst, (const int4*)dst, counts, E, nq);
    scan_a<<<B, 256, 0, stream>>>(counts, bsums, N);
    scan_b<<<1, 256, 0, stream>>>(bsums, boffs, offsets + N, B);
    scan_c<<<B, 256, 0, stream>>>(counts, boffs, offsets, cursor, N);
    dinv_kernel<<<(N + 255) / 256, 256, 0, stream>>>(counts, dinv, N);
    scatter_kernel<<<2048, 256, 0, stream>>>(src, dst, (const int4*)src, (const int4*)dst,
                                             cursor, ssrc, E, nq);

    gemm_scale<<<(N + 15) / 16, 256, 0, stream>>>((const float4*)x, (const float4*)W1, dinv,
                                                  (float4*)y, N);
    aggregate_kernel<<<(N + 3) / 4, 256, 0, stream>>>((const float4*)y, ssrc, offsets, dinv,
                                                      (const float4*)b1, (float4*)h, N);
    gemm_scale<<<(N + 15) / 16, 256, 0, stream>>>((const float4*)h, (const float4*)W2, dinv,
                                                  (float4*)y, N);
    aggregate_kernel<<<(N + 3) / 4, 256, 0, stream>>>((const float4*)y, ssrc, offsets, dinv,
                                                      (const float4*)b2, (float4*)h, N);

    int waves = (N + 255) / 256;
    pool_kernel<<<(waves + 3) / 4, 256, 0, stream>>>((const float4*)h, batch, psums, pcnt, N);
    final_kernel<<<64, 64, 0, stream>>>(psums, pcnt, Wp, bp, (float*)d_out);
}